// Round 1
// baseline (16935.573 us; speedup 1.0000x reference)
//
#include <hip/hip_runtime.h>
#include <math.h>

#define B 32
#define T 128
#define H 512
#define E 512
#define ODIM 256
#define STEPS 16
#define G3 1536  // 3*H

typedef float4 f4;

__device__ __forceinline__ float sigmoidf_(float x) { return 1.0f / (1.0f + __expf(-x)); }

// ---------------- kproj = enc @ Wk.T  [B*T, H] ----------------
__global__ void kproj_kernel(const float* __restrict__ enc, const float* __restrict__ Wk,
                             float* __restrict__ kproj) {
    __shared__ __align__(16) float sh[H];
    int r = blockIdx.x;            // 0..B*T-1
    int tid = threadIdx.x;         // 256
    const float* row = enc + (size_t)r * H;
    sh[tid] = row[tid];
    sh[tid + 256] = row[tid + 256];
    __syncthreads();
    for (int cc = 0; cc < 2; ++cc) {
        int c = tid + cc * 256;
        const f4* wr = (const f4*)(Wk + (size_t)c * H);
        const f4* hv = (const f4*)sh;
        float acc = 0.f;
#pragma unroll 4
        for (int k = 0; k < H / 4; ++k) {
            f4 w = wr[k]; f4 h = hv[k];
            acc += w.x * h.x + w.y * h.y + w.z * h.z + w.w * h.w;
        }
        kproj[(size_t)r * H + c] = acc;
    }
}

// ---------------- inp0 = emb(ones)*SOS, same for every b ----------------
__global__ void inp0_kernel(const float* __restrict__ emb_W, const float* __restrict__ emb_b,
                            float* __restrict__ inp) {
    int e = threadIdx.x;  // 512
    const f4* row = (const f4*)(emb_W + (size_t)e * ODIM);
    float acc = emb_b[e];
    for (int k = 0; k < ODIM / 4; ++k) { f4 w = row[k]; acc += w.x + w.y + w.z + w.w; }
    for (int b = 0; b < B; ++b) inp[b * H + e] = acc;
}

// ---------------- gi_emb[b,g] = inp[b,:] @ Wi0[g, 512:1024] ----------------
__global__ void gi_emb_kernel(const float* __restrict__ inp, const float* __restrict__ Wi0,
                              float* __restrict__ gi) {
    __shared__ __align__(16) float sh[E];
    int b = blockIdx.x, tid = threadIdx.x;  // 256
    sh[tid] = inp[b * E + tid];
    sh[tid + 256] = inp[b * E + tid + 256];
    __syncthreads();
    for (int rr = 0; rr < 6; ++rr) {
        int g = tid + rr * 256;
        const f4* wr = (const f4*)(Wi0 + (size_t)g * (E + H) + H);
        float acc = 0.f;
#pragma unroll 4
        for (int k = 0; k < E / 4; ++k) {
            f4 w = wr[k]; f4 x = ((const f4*)sh)[k];
            acc += w.x * x.x + w.y * x.y + w.z * x.z + w.w * x.w;
        }
        gi[b * G3 + g] = acc;
    }
}

// ---------------- fused attention: q -> scores -> softmax -> context -> gi_ctx ----------------
__global__ void attn_kernel(const float* __restrict__ h1, const float* __restrict__ Wq,
                            const float* __restrict__ kproj, const float* __restrict__ wv,
                            const float* __restrict__ enc, const float* __restrict__ Wi0,
                            const float* __restrict__ bi0, float* __restrict__ gi_ctx,
                            float* __restrict__ attn_out) {
    __shared__ __align__(16) float sh_h[H];
    __shared__ __align__(16) float sh_q[H];
    __shared__ __align__(16) float sh_wv[H];
    __shared__ __align__(16) float sh_ctx[H];
    __shared__ __align__(16) float sh_p[512];
    __shared__ float sh_sc[T];
    __shared__ float sh_w[T];
    __shared__ float sh_red[1];
    int b = blockIdx.x, tid = threadIdx.x;  // 512 threads
    sh_h[tid] = h1[b * H + tid];
    sh_wv[tid] = wv[tid];
    __syncthreads();
    // q[b,j]
    {
        const f4* wr = (const f4*)(Wq + (size_t)tid * H);
        float acc = 0.f;
#pragma unroll 4
        for (int k = 0; k < H / 4; ++k) {
            f4 w = wr[k]; f4 h = ((const f4*)sh_h)[k];
            acc += w.x * h.x + w.y * h.y + w.z * h.z + w.w * h.w;
        }
        sh_q[tid] = acc;
    }
    __syncthreads();
    // scores partials: thread -> (t = tid>>2, part = tid&3, 128 h each)
    {
        int t = tid >> 2, p = tid & 3;
        const f4* kp = (const f4*)(kproj + ((size_t)(b * T + t)) * H + p * 128);
        const f4* qv = (const f4*)(sh_q + p * 128);
        const f4* wv4 = (const f4*)(sh_wv + p * 128);
        float acc = 0.f;
        for (int k = 0; k < 32; ++k) {
            f4 kk = kp[k]; f4 q = qv[k]; f4 w = wv4[k];
            acc += tanhf(q.x + kk.x) * w.x + tanhf(q.y + kk.y) * w.y +
                   tanhf(q.z + kk.z) * w.z + tanhf(q.w + kk.w) * w.w;
        }
        sh_p[tid] = acc;
    }
    __syncthreads();
    if (tid < T) sh_sc[tid] = sh_p[tid * 4] + sh_p[tid * 4 + 1] + sh_p[tid * 4 + 2] + sh_p[tid * 4 + 3];
    __syncthreads();
    if (tid < 64) {
        float m = fmaxf(sh_sc[tid], sh_sc[tid + 64]);
        for (int off = 32; off; off >>= 1) m = fmaxf(m, __shfl_xor(m, off));
        if (tid == 0) sh_red[0] = m;
    }
    __syncthreads();
    float mx = sh_red[0];
    if (tid < T) sh_w[tid] = __expf(sh_sc[tid] - mx);
    __syncthreads();
    if (tid < 64) {
        float s = sh_w[tid] + sh_w[tid + 64];
        for (int off = 32; off; off >>= 1) s += __shfl_xor(s, off);
        if (tid == 0) sh_red[0] = s;
    }
    __syncthreads();
    float inv = 1.0f / sh_red[0];
    if (tid < T) {
        float w = sh_w[tid] * inv;
        sh_w[tid] = w;
        attn_out[b * T + tid] = w;
    }
    __syncthreads();
    // context[b,j] = sum_t w[t] * enc[b,t,j]
    {
        float acc = 0.f;
        const float* ep = enc + (size_t)b * T * H + tid;
        for (int t = 0; t < T; ++t) acc += sh_w[t] * ep[(size_t)t * H];
        sh_ctx[tid] = acc;
    }
    __syncthreads();
    // gi_ctx[b,g] = bi0[g] + ctx @ Wi0[g, 0:512]
    for (int rr = 0; rr < 3; ++rr) {
        int g = rr * 512 + tid;
        const f4* wr = (const f4*)(Wi0 + (size_t)g * (E + H));
        float acc = bi0[g];
#pragma unroll 4
        for (int k = 0; k < H / 4; ++k) {
            f4 w = wr[k]; f4 c = ((const f4*)sh_ctx)[k];
            acc += w.x * c.x + w.y * c.y + w.z * c.z + w.w * c.w;
        }
        gi_ctx[b * G3 + g] = acc;
    }
}

// ---------------- fused dual GRU cell: blocks [0,nb0) -> layer0 step t, rest -> layer1 step t-1 ----------------
__global__ void __launch_bounds__(256) cell_kernel(
    int nb0,
    const float* __restrict__ h0_src, float* __restrict__ h0_dst,
    const float* __restrict__ h1_src, float* __restrict__ h1_dst,
    const float* __restrict__ gi_emb_t, const float* __restrict__ gi_ctx,
    const float* __restrict__ Wh0, const float* __restrict__ bh0,
    const float* __restrict__ Wi1, const float* __restrict__ bi1,
    const float* __restrict__ Wh1, const float* __restrict__ bh1) {
    __shared__ __align__(16) float sh[8192];  // 32 KB
    int tid = threadIdx.x;
    if ((int)blockIdx.x < nb0) {
        // ---- layer0 cell: gh = h0 @ Wh0.T ; gi precomputed (gi_ctx + gi_emb_t) ----
        int bid = blockIdx.x;
        int bc = bid >> 4, jc = bid & 15;
        for (int ii = 0; ii < 16; ++ii) {
            int flat = ii * 256 + tid;
            sh[flat] = h0_src[bc * 8 * H + flat];
        }
        __syncthreads();
        int bb = tid >> 5, jj = tid & 31;
        int b = bc * 8 + bb, j = jc * 32 + jj;
        float ar = bh0[j], az = bh0[H + j], an = bh0[2 * H + j];
        const f4* wr = (const f4*)(Wh0 + (size_t)j * H);
        const f4* wz = (const f4*)(Wh0 + (size_t)(H + j) * H);
        const f4* wn = (const f4*)(Wh0 + (size_t)(2 * H + j) * H);
        const f4* hv = (const f4*)(sh + bb * H);
#pragma unroll 4
        for (int k = 0; k < H / 4; ++k) {
            f4 h = hv[k]; f4 r = wr[k]; f4 z = wz[k]; f4 n = wn[k];
            ar += h.x * r.x + h.y * r.y + h.z * r.z + h.w * r.w;
            az += h.x * z.x + h.y * z.y + h.z * z.z + h.w * z.w;
            an += h.x * n.x + h.y * n.y + h.z * n.z + h.w * n.w;
        }
        float gir = gi_ctx[b * G3 + j] + gi_emb_t[b * G3 + j];
        float giz = gi_ctx[b * G3 + H + j] + gi_emb_t[b * G3 + H + j];
        float gin = gi_ctx[b * G3 + 2 * H + j] + gi_emb_t[b * G3 + 2 * H + j];
        float r = sigmoidf_(gir + ar);
        float z = sigmoidf_(giz + az);
        float n = tanhf(gin + r * an);
        float hp = sh[bb * H + j];
        h0_dst[b * H + j] = (1.0f - z) * n + z * hp;
    } else {
        // ---- layer1 cell: x = y0(t-1) = h0_src ; full gi + gh dots ----
        int bid = blockIdx.x - nb0;
        int bc = bid >> 4, jc = bid & 15;
        for (int ii = 0; ii < 16; ++ii) {
            int flat = ii * 256 + tid;
            sh[flat] = h0_src[bc * 8 * H + flat];
            sh[4096 + flat] = h1_src[bc * 8 * H + flat];
        }
        __syncthreads();
        int bb = tid >> 5, jj = tid & 31;
        int b = bc * 8 + bb, j = jc * 32 + jj;
        float air = bi1[j], aiz = bi1[H + j], ain = bi1[2 * H + j];
        float ahr = bh1[j], ahz = bh1[H + j], ahn = bh1[2 * H + j];
        const f4* uir = (const f4*)(Wi1 + (size_t)j * H);
        const f4* uiz = (const f4*)(Wi1 + (size_t)(H + j) * H);
        const f4* uin = (const f4*)(Wi1 + (size_t)(2 * H + j) * H);
        const f4* uhr = (const f4*)(Wh1 + (size_t)j * H);
        const f4* uhz = (const f4*)(Wh1 + (size_t)(H + j) * H);
        const f4* uhn = (const f4*)(Wh1 + (size_t)(2 * H + j) * H);
        const f4* xv = (const f4*)(sh + bb * H);
        const f4* hv = (const f4*)(sh + 4096 + bb * H);
#pragma unroll 2
        for (int k = 0; k < H / 4; ++k) {
            f4 x = xv[k]; f4 h = hv[k];
            f4 a = uir[k]; air += x.x * a.x + x.y * a.y + x.z * a.z + x.w * a.w;
            f4 c = uiz[k]; aiz += x.x * c.x + x.y * c.y + x.z * c.z + x.w * c.w;
            f4 d = uin[k]; ain += x.x * d.x + x.y * d.y + x.z * d.z + x.w * d.w;
            f4 e = uhr[k]; ahr += h.x * e.x + h.y * e.y + h.z * e.z + h.w * e.w;
            f4 f = uhz[k]; ahz += h.x * f.x + h.y * f.y + h.z * f.z + h.w * f.w;
            f4 g = uhn[k]; ahn += h.x * g.x + h.y * g.y + h.z * g.z + h.w * g.w;
        }
        float r = sigmoidf_(air + ahr);
        float z = sigmoidf_(aiz + ahz);
        float n = tanhf(ain + r * ahn);
        float hp = sh[4096 + bb * H + j];
        h1_dst[b * H + j] = (1.0f - z) * n + z * hp;
    }
}

// ---------------- tail: lin -> teacher force -> out ; emb -> gi_emb_next ----------------
__global__ void tail_kernel(const float* __restrict__ h1, const float* __restrict__ last_W,
                            const float* __restrict__ last_b, const float* __restrict__ target_step,
                            const int* __restrict__ mask_step, const float* __restrict__ emb_W,
                            const float* __restrict__ emb_b, const float* __restrict__ Wi0,
                            float* __restrict__ out_step, float* __restrict__ gi_emb_next,
                            int do_next) {
    __shared__ __align__(16) float sh_h[H];
    __shared__ __align__(16) float sh_f[ODIM];
    __shared__ __align__(16) float sh_inp[E];
    int b = blockIdx.x, tid = threadIdx.x;  // 256
    sh_h[tid] = h1[b * H + tid];
    sh_h[tid + 256] = h1[b * H + tid + 256];
    __syncthreads();
    {
        int o = tid;
        const f4* wr = (const f4*)(last_W + (size_t)o * H);
        float acc = last_b[o];
#pragma unroll 4
        for (int k = 0; k < H / 4; ++k) {
            f4 w = wr[k]; f4 h = ((const f4*)sh_h)[k];
            acc += w.x * h.x + w.y * h.y + w.z * h.z + w.w * h.w;
        }
        float f = (mask_step[b] != 0) ? target_step[b * ODIM + o] : acc;
        out_step[b * ODIM + o] = f;
        sh_f[o] = f;
    }
    __syncthreads();
    if (!do_next) return;
    for (int rr = 0; rr < 2; ++rr) {
        int e = rr * 256 + tid;
        const f4* wr = (const f4*)(emb_W + (size_t)e * ODIM);
        float acc = emb_b[e];
#pragma unroll 4
        for (int k = 0; k < ODIM / 4; ++k) {
            f4 w = wr[k]; f4 f = ((const f4*)sh_f)[k];
            acc += w.x * f.x + w.y * f.y + w.z * f.z + w.w * f.w;
        }
        sh_inp[e] = acc;
    }
    __syncthreads();
    for (int rr = 0; rr < 6; ++rr) {
        int g = rr * 256 + tid;
        const f4* wr = (const f4*)(Wi0 + (size_t)g * (E + H) + H);
        float acc = 0.f;
#pragma unroll 4
        for (int k = 0; k < E / 4; ++k) {
            f4 w = wr[k]; f4 x = ((const f4*)sh_inp)[k];
            acc += w.x * x.x + w.y * x.y + w.z * x.z + w.w * x.w;
        }
        gi_emb_next[b * G3 + g] = acc;
    }
}

__global__ void copy_hidden_kernel(const float* __restrict__ h0, const float* __restrict__ h1,
                                   float* __restrict__ dst) {
    int i = blockIdx.x * 256 + threadIdx.x;  // 64 blocks * 256 = 16384
    dst[i] = h0[i];
    dst[B * H + i] = h1[i];
}

extern "C" void kernel_launch(void* const* d_in, const int* in_sizes, int n_in,
                              void* d_out_v, int out_size, void* d_ws, size_t ws_size,
                              hipStream_t stream) {
    const float* enc = (const float*)d_in[0];
    const float* hidden = (const float*)d_in[1];
    const float* target = (const float*)d_in[2];
    const float* Wq = (const float*)d_in[3];
    const float* Wk = (const float*)d_in[4];
    const float* wv = (const float*)d_in[5];
    const float* emb_W = (const float*)d_in[6];
    const float* emb_b = (const float*)d_in[7];
    const float* Wi0 = (const float*)d_in[8];
    const float* Wh0 = (const float*)d_in[9];
    const float* bi0 = (const float*)d_in[10];
    const float* bh0 = (const float*)d_in[11];
    const float* Wi1 = (const float*)d_in[12];
    const float* Wh1 = (const float*)d_in[13];
    const float* bi1 = (const float*)d_in[14];
    const float* bh1 = (const float*)d_in[15];
    const float* last_W = (const float*)d_in[16];
    const float* last_b = (const float*)d_in[17];
    const int* tmask = (const int*)d_in[18];

    float* out = (float*)d_out_v;
    float* out_hidden = out + (size_t)STEPS * B * ODIM;  // +131072
    float* out_attn = out_hidden + (size_t)2 * B * H;    // +163840

    float* ws = (float*)d_ws;
    float* kproj = ws;                                  // B*T*H = 2097152
    float* gi_emb = kproj + (size_t)B * T * H;          // 16 * B*G3 = 786432
    float* gi_ctx = gi_emb + (size_t)16 * B * G3;       // B*G3 = 49152
    float* h0buf = gi_ctx + (size_t)B * G3;             // 2 * B*H
    float* h1buf = h0buf + (size_t)2 * B * H;           // 2 * B*H
    float* inp0 = h1buf + (size_t)2 * B * H;            // B*H
    // total ~12.1 MB of ws

    hipMemcpyAsync(h0buf, hidden, (size_t)B * H * sizeof(float), hipMemcpyDeviceToDevice, stream);
    hipMemcpyAsync(h1buf, hidden + (size_t)B * H, (size_t)B * H * sizeof(float),
                   hipMemcpyDeviceToDevice, stream);

    kproj_kernel<<<B * T, 256, 0, stream>>>(enc, Wk, kproj);
    inp0_kernel<<<1, 512, 0, stream>>>(emb_W, emb_b, inp0);
    gi_emb_kernel<<<B, 256, 0, stream>>>(inp0, Wi0, gi_emb);

    int p0 = 0, p1 = 0;
    for (int i = 0; i < STEPS; ++i) {
        attn_kernel<<<B, 512, 0, stream>>>(h1buf + (size_t)p1 * B * H, Wq, kproj, wv, enc, Wi0,
                                           bi0, gi_ctx, out_attn + (size_t)i * B * T);
        for (int t = 0; t <= i + 1; ++t) {
            int nb0 = (t <= i) ? 64 : 0;
            int nb1 = (t >= 1) ? 64 : 0;
            int tge = (t < 15) ? t : 15;  // clamp unused ptr at t==16
            cell_kernel<<<nb0 + nb1, 256, 0, stream>>>(
                nb0, h0buf + (size_t)p0 * B * H, h0buf + (size_t)(p0 ^ 1) * B * H,
                h1buf + (size_t)p1 * B * H, h1buf + (size_t)(p1 ^ 1) * B * H,
                gi_emb + (size_t)tge * B * G3, gi_ctx, Wh0, bh0, Wi1, bi1, Wh1, bh1);
            if (nb0) p0 ^= 1;
            if (nb1) p1 ^= 1;
        }
        tail_kernel<<<B, 256, 0, stream>>>(
            h1buf + (size_t)p1 * B * H, last_W, last_b, target + (size_t)i * B * ODIM,
            tmask + i * B, emb_W, emb_b, Wi0, out + (size_t)i * B * ODIM,
            gi_emb + (size_t)((i + 1 < 16) ? (i + 1) : 15) * B * G3, (i < STEPS - 1) ? 1 : 0);
    }
    copy_hidden_kernel<<<64, 256, 0, stream>>>(h0buf + (size_t)p0 * B * H,
                                               h1buf + (size_t)p1 * B * H, out_hidden);
}

// Round 2
// 5349.620 us; speedup vs baseline: 3.1658x; 3.1658x over previous
//
#include <hip/hip_runtime.h>
#include <math.h>

#define B 32
#define T 128
#define H 512
#define E 512
#define ODIM 256
#define STEPS 16
#define G3 1536  // 3*H
#define BH (B * H)

typedef float4 f4;

__device__ __forceinline__ float sigmoidf_(float x) { return 1.0f / (1.0f + __expf(-x)); }

// ---------------- generic 32x32 tiled transpose: out[c*R+r] = in[r*ldin+c] ----------------
__global__ void transpose_kernel(const float* __restrict__ in, float* __restrict__ out,
                                 int R, int C, int ldin) {
    __shared__ float tile[32][33];
    int r0 = blockIdx.x * 32, c0 = blockIdx.y * 32;
    int tx = threadIdx.x & 31, ty = threadIdx.x >> 5;  // 32x8
#pragma unroll
    for (int k = 0; k < 4; ++k) {
        int r = r0 + ty + k * 8;
        tile[ty + k * 8][tx] = in[(size_t)r * ldin + c0 + tx];
    }
    __syncthreads();
#pragma unroll
    for (int k = 0; k < 4; ++k) {
        int c = c0 + ty + k * 8;
        out[(size_t)c * R + r0 + tx] = tile[tx][ty + k * 8];
    }
}

// ---------------- kpT[b][c][t] = sum_k enc[b*T+t][k] * WkT[k][c] ----------------
// tiled GEMM: M=4096 (r=b*128+t), N=512 (c), K=512
__global__ void __launch_bounds__(256) kproj_gemm_kernel(const float* __restrict__ A,
                                                         const float* __restrict__ Bt,
                                                         float* __restrict__ kpT) {
    __shared__ float As[64][68];
    __shared__ float Bs[64][64];
    int r0 = blockIdx.x * 64, c0 = blockIdx.y * 64;
    int tid = threadIdx.x;
    int tx = tid & 15, ty = tid >> 4;  // 16x16, 4x4 micro-tile
    float acc[4][4] = {};
    for (int k0 = 0; k0 < 512; k0 += 64) {
#pragma unroll
        for (int i = 0; i < 4; ++i) {
            int row = i * 16 + ty, col = tx * 4;
            f4 av = *(const f4*)(A + (size_t)(r0 + row) * 512 + k0 + col);
            As[row][col] = av.x; As[row][col + 1] = av.y; As[row][col + 2] = av.z; As[row][col + 3] = av.w;
            f4 bv = *(const f4*)(Bt + (size_t)(k0 + row) * 512 + c0 + col);
            *(f4*)&Bs[row][col] = bv;
        }
        __syncthreads();
#pragma unroll 8
        for (int kk = 0; kk < 64; ++kk) {
            float a[4];
#pragma unroll
            for (int i = 0; i < 4; ++i) a[i] = As[ty * 4 + i][kk];
            f4 bv = *(const f4*)&Bs[kk][tx * 4];
#pragma unroll
            for (int i = 0; i < 4; ++i) {
                acc[i][0] += a[i] * bv.x; acc[i][1] += a[i] * bv.y;
                acc[i][2] += a[i] * bv.z; acc[i][3] += a[i] * bv.w;
            }
        }
        __syncthreads();
    }
#pragma unroll
    for (int i = 0; i < 4; ++i) {
        int r = r0 + ty * 4 + i;
        int b = r >> 7, t = r & 127;
#pragma unroll
        for (int j = 0; j < 4; ++j) {
            int c = c0 + tx * 4 + j;
            kpT[((size_t)b * H + c) * T + t] = acc[i][j];
        }
    }
}

// ---------------- init: copy hidden, inp0 = emb(ones), gi_emb0 ----------------
__global__ void __launch_bounds__(512) init_kernel(const float* __restrict__ hidden,
                                                   const float* __restrict__ embWT,
                                                   const float* __restrict__ emb_b,
                                                   const float* __restrict__ Wi0bT,
                                                   float* __restrict__ h0, float* __restrict__ h1,
                                                   float* __restrict__ gi_emb0) {
    __shared__ float sh_inp[E];
    int b = blockIdx.x, tid = threadIdx.x;
    h0[b * H + tid] = hidden[b * H + tid];
    h1[b * H + tid] = hidden[BH + b * H + tid];
    float acc = emb_b[tid];
#pragma unroll 8
    for (int o = 0; o < ODIM; ++o) acc += embWT[o * E + tid];
    sh_inp[tid] = acc;
    __syncthreads();
    float a0 = 0.f, a1 = 0.f, a2 = 0.f;
    int g = tid;
#pragma unroll 8
    for (int e = 0; e < E; ++e) {
        float c = sh_inp[e];
        const float* w = Wi0bT + e * G3 + g;
        a0 += c * w[0]; a1 += c * w[512]; a2 += c * w[1024];
    }
    gi_emb0[b * G3 + g] = a0;
    gi_emb0[b * G3 + 512 + g] = a1;
    gi_emb0[b * G3 + 1024 + g] = a2;
}

// ---------------- attn (blocks < nb_attn) + tail for prev step (blocks >= nb_attn) ----------------
__global__ void __launch_bounds__(512) attn_tail_kernel(
    int nb_attn, const float* __restrict__ h1_cur,
    const float* __restrict__ WqT, const float* __restrict__ kpT, const float* __restrict__ wv,
    const float* __restrict__ enc, const float* __restrict__ Wi0aT, const float* __restrict__ bi0,
    float* __restrict__ gi_ctx, float* __restrict__ attn_out,
    const float* __restrict__ lastWT, const float* __restrict__ last_b,
    const float* __restrict__ target_step, const int* __restrict__ mask_step,
    const float* __restrict__ embWT, const float* __restrict__ emb_b,
    const float* __restrict__ Wi0bT, float* __restrict__ out_step,
    float* __restrict__ gi_emb_next, int do_emb) {
    __shared__ __align__(16) float sh_h[H];
    __shared__ __align__(16) float sh_q[H];
    __shared__ __align__(16) float sh_wv[H];
    __shared__ __align__(16) float sh_p2[512];
    __shared__ float sh_sc[T];
    __shared__ float sh_w[T];
    __shared__ __align__(16) float sh_ctx[H];
    __shared__ float sh_f[ODIM];
    __shared__ float sh_red[2];
    int tid = threadIdx.x;
    if ((int)blockIdx.x < nb_attn) {
        int b = blockIdx.x;
        sh_h[tid] = h1_cur[b * H + tid];
        sh_wv[tid] = wv[tid];
        __syncthreads();
        // q[j] = sum_k h[k] WqT[k][j]
        {
            float acc = 0.f;
#pragma unroll 8
            for (int k = 0; k < H; ++k) acc += sh_h[k] * WqT[k * H + tid];
            sh_q[tid] = acc;
        }
        __syncthreads();
        // scores partials: grp over j-quarters, lanes over t (coalesced on kpT)
        {
            int grp = tid >> 7, t = tid & 127;
            const float* kp = kpT + (size_t)b * H * T + t;
            float sa = 0.f;
#pragma unroll 4
            for (int jj = 0; jj < 128; ++jj) {
                int j = grp * 128 + jj;
                sa += tanhf(sh_q[j] + kp[(size_t)j * T]) * sh_wv[j];
            }
            sh_p2[tid] = sa;
        }
        __syncthreads();
        if (tid < T) sh_sc[tid] = sh_p2[tid] + sh_p2[tid + 128] + sh_p2[tid + 256] + sh_p2[tid + 384];
        __syncthreads();
        if (tid < 64) {
            float m = fmaxf(sh_sc[tid], sh_sc[tid + 64]);
            for (int off = 32; off; off >>= 1) m = fmaxf(m, __shfl_xor(m, off));
            if (tid == 0) sh_red[0] = m;
        }
        __syncthreads();
        if (tid < T) sh_w[tid] = __expf(sh_sc[tid] - sh_red[0]);
        __syncthreads();
        if (tid < 64) {
            float s = sh_w[tid] + sh_w[tid + 64];
            for (int off = 32; off; off >>= 1) s += __shfl_xor(s, off);
            if (tid == 0) sh_red[1] = s;
        }
        __syncthreads();
        if (tid < T) {
            float w = sh_w[tid] / sh_red[1];
            sh_w[tid] = w;
            attn_out[b * T + tid] = w;
        }
        __syncthreads();
        // ctx[c] = sum_t w[t] enc[b][t][c]  (coalesced over c)
        {
            float acc = 0.f;
            const float* ep = enc + (size_t)b * T * H + tid;
#pragma unroll 8
            for (int t = 0; t < T; ++t) acc += sh_w[t] * ep[(size_t)t * H];
            sh_ctx[tid] = acc;
        }
        __syncthreads();
        // gi_ctx[b][g] = bi0[g] + ctx @ Wi0aT
        {
            int g = tid;
            float a0 = bi0[g], a1 = bi0[512 + g], a2 = bi0[1024 + g];
#pragma unroll 8
            for (int k = 0; k < H; ++k) {
                float c = sh_ctx[k];
                const float* w = Wi0aT + k * G3 + g;
                a0 += c * w[0]; a1 += c * w[512]; a2 += c * w[1024];
            }
            gi_ctx[b * G3 + g] = a0;
            gi_ctx[b * G3 + 512 + g] = a1;
            gi_ctx[b * G3 + 1024 + g] = a2;
        }
    } else {
        int b = blockIdx.x - nb_attn;
        sh_h[tid] = h1_cur[b * H + tid];
        __syncthreads();
        if (tid < ODIM) {
            float acc = last_b[tid];
#pragma unroll 8
            for (int k = 0; k < H; ++k) acc += sh_h[k] * lastWT[k * ODIM + tid];
            float f = (mask_step[b] != 0) ? target_step[b * ODIM + tid] : acc;
            out_step[b * ODIM + tid] = f;
            sh_f[tid] = f;
        }
        __syncthreads();
        if (!do_emb) return;
        {
            float acc = emb_b[tid];
#pragma unroll 8
            for (int o = 0; o < ODIM; ++o) acc += sh_f[o] * embWT[o * E + tid];
            sh_ctx[tid] = acc;  // reuse as inp
        }
        __syncthreads();
        {
            int g = tid;
            float a0 = 0.f, a1 = 0.f, a2 = 0.f;
#pragma unroll 8
            for (int e = 0; e < E; ++e) {
                float c = sh_ctx[e];
                const float* w = Wi0bT + e * G3 + g;
                a0 += c * w[0]; a1 += c * w[512]; a2 += c * w[1024];
            }
            gi_emb_next[b * G3 + g] = a0;
            gi_emb_next[b * G3 + 512 + g] = a1;
            gi_emb_next[b * G3 + 1024 + g] = a2;
        }
    }
}

// ---------------- fused dual GRU cell, coalesced WT + split-k ----------------
// layer0 blocks [0,nb0): 8 bgroups x 16 jchunks; layer1 blocks [nb0, nb0+128)
// block = 4b x 2kh x 32jj (tid = b2*64 + kh*32 + jj)
__global__ void __launch_bounds__(256) cell_kernel(
    int nb0,
    const float* __restrict__ h0_src, float* __restrict__ h0_dst,
    const float* __restrict__ h1_src, float* __restrict__ h1_dst,
    const float* __restrict__ gi_emb_t, const float* __restrict__ gi_ctx,
    const float* __restrict__ Wh0T, const float* __restrict__ bh0,
    const float* __restrict__ Wi1T, const float* __restrict__ bi1,
    const float* __restrict__ Wh1T, const float* __restrict__ bh1) {
    __shared__ __align__(16) float sh[4096 + 1536];  // x/h stage + partials
    float* part = sh + 4096;
    int tid = threadIdx.x;
    int jj = tid & 31, kh = (tid >> 5) & 1, b2 = tid >> 6;
    if ((int)blockIdx.x < nb0) {
        int bid = blockIdx.x;
        int bg = bid >> 4, jch = bid & 15;
        {   // stage h0: 4 x 512
            const f4* src = (const f4*)(h0_src + (size_t)bg * 4 * H);
            f4* dst = (f4*)sh;
            dst[tid] = src[tid];
            dst[tid + 256] = src[tid + 256];
        }
        __syncthreads();
        int j = jch * 32 + jj;
        float ar = 0.f, az = 0.f, an = 0.f;
        const float* wp = Wh0T + (size_t)(kh * 256) * G3 + j;
        const float* hp = sh + b2 * H + kh * 256;
#pragma unroll 8
        for (int k = 0; k < 256; ++k) {
            float h = hp[k];
            const float* w = wp + k * G3;
            ar += h * w[0]; az += h * w[512]; an += h * w[1024];
        }
        part[tid * 3] = ar; part[tid * 3 + 1] = az; part[tid * 3 + 2] = an;
        __syncthreads();
        if (tid < 128) {
            int rb2 = tid >> 5, rjj = tid & 31;
            int t0 = rb2 * 64 + rjj, t1 = t0 + 32;
            int b = bg * 4 + rb2, jg = jch * 32 + rjj;
            float ghr = part[t0 * 3] + part[t1 * 3] + bh0[jg];
            float ghz = part[t0 * 3 + 1] + part[t1 * 3 + 1] + bh0[H + jg];
            float ghn = part[t0 * 3 + 2] + part[t1 * 3 + 2] + bh0[2 * H + jg];
            float gir = gi_ctx[b * G3 + jg] + gi_emb_t[b * G3 + jg];
            float giz = gi_ctx[b * G3 + H + jg] + gi_emb_t[b * G3 + H + jg];
            float gin = gi_ctx[b * G3 + 2 * H + jg] + gi_emb_t[b * G3 + 2 * H + jg];
            float r = sigmoidf_(gir + ghr);
            float z = sigmoidf_(giz + ghz);
            float n = tanhf(gin + r * ghn);
            float hprev = sh[rb2 * H + jg];
            h0_dst[b * H + jg] = (1.0f - z) * n + z * hprev;
        }
    } else {
        int bid = blockIdx.x - nb0;
        int bg = bid >> 4, jch = bid & 15;
        {   // stage x = y0(t-1) and h1: each 4 x 512
            const f4* sx = (const f4*)(h0_src + (size_t)bg * 4 * H);
            const f4* shh = (const f4*)(h1_src + (size_t)bg * 4 * H);
            f4* dx = (f4*)sh;
            f4* dh = (f4*)(sh + 2048);
            dx[tid] = sx[tid]; dx[tid + 256] = sx[tid + 256];
            dh[tid] = shh[tid]; dh[tid + 256] = shh[tid + 256];
        }
        __syncthreads();
        int j = jch * 32 + jj;
        float air = 0.f, aiz = 0.f, ain = 0.f, ahr = 0.f, ahz = 0.f, ahn = 0.f;
        const float* wip = Wi1T + (size_t)(kh * 256) * G3 + j;
        const float* whp = Wh1T + (size_t)(kh * 256) * G3 + j;
        const float* xp = sh + b2 * H + kh * 256;
        const float* hp = sh + 2048 + b2 * H + kh * 256;
#pragma unroll 4
        for (int k = 0; k < 256; ++k) {
            float x = xp[k], h = hp[k];
            const float* wi = wip + k * G3;
            const float* wh = whp + k * G3;
            air += x * wi[0]; aiz += x * wi[512]; ain += x * wi[1024];
            ahr += h * wh[0]; ahz += h * wh[512]; ahn += h * wh[1024];
        }
        float* p6 = part + tid * 6;
        p6[0] = air; p6[1] = aiz; p6[2] = ain; p6[3] = ahr; p6[4] = ahz; p6[5] = ahn;
        __syncthreads();
        if (tid < 128) {
            int rb2 = tid >> 5, rjj = tid & 31;
            int t0 = rb2 * 64 + rjj, t1 = t0 + 32;
            int b = bg * 4 + rb2, jg = jch * 32 + rjj;
            const float* q0 = part + t0 * 6;
            const float* q1 = part + t1 * 6;
            float ir = q0[0] + q1[0] + bi1[jg];
            float iz = q0[1] + q1[1] + bi1[H + jg];
            float in_ = q0[2] + q1[2] + bi1[2 * H + jg];
            float hr = q0[3] + q1[3] + bh1[jg];
            float hz = q0[4] + q1[4] + bh1[H + jg];
            float hn = q0[5] + q1[5] + bh1[2 * H + jg];
            float r = sigmoidf_(ir + hr);
            float z = sigmoidf_(iz + hz);
            float n = tanhf(in_ + r * hn);
            float hprev = sh[2048 + rb2 * H + jg];
            h1_dst[b * H + jg] = (1.0f - z) * n + z * hprev;
        }
    }
}

__global__ void copy_hidden_kernel(const float* __restrict__ h0, const float* __restrict__ h1,
                                   float* __restrict__ dst) {
    int i = blockIdx.x * 256 + threadIdx.x;
    dst[i] = h0[i];
    dst[BH + i] = h1[i];
}

extern "C" void kernel_launch(void* const* d_in, const int* in_sizes, int n_in,
                              void* d_out_v, int out_size, void* d_ws, size_t ws_size,
                              hipStream_t stream) {
    const float* enc = (const float*)d_in[0];
    const float* hidden = (const float*)d_in[1];
    const float* target = (const float*)d_in[2];
    const float* Wq = (const float*)d_in[3];
    const float* Wk = (const float*)d_in[4];
    const float* wv = (const float*)d_in[5];
    const float* emb_W = (const float*)d_in[6];
    const float* emb_b = (const float*)d_in[7];
    const float* Wi0 = (const float*)d_in[8];
    const float* Wh0 = (const float*)d_in[9];
    const float* bi0 = (const float*)d_in[10];
    const float* bh0 = (const float*)d_in[11];
    const float* Wi1 = (const float*)d_in[12];
    const float* Wh1 = (const float*)d_in[13];
    const float* bi1 = (const float*)d_in[14];
    const float* bh1 = (const float*)d_in[15];
    const float* last_W = (const float*)d_in[16];
    const float* last_b = (const float*)d_in[17];
    const int* tmask = (const int*)d_in[18];

    float* out = (float*)d_out_v;
    float* out_hidden = out + (size_t)STEPS * B * ODIM;
    float* out_attn = out_hidden + (size_t)2 * BH;

    float* ws = (float*)d_ws;
    float* kpT = ws;                        // 2,097,152
    float* WqT = kpT + 2097152;             // 262,144
    float* WkT = WqT + 262144;              // 262,144
    float* Wi0aT = WkT + 262144;            // 786,432
    float* Wi0bT = Wi0aT + 786432;          // 786,432
    float* Wh0T = Wi0bT + 786432;           // 786,432
    float* Wi1T = Wh0T + 786432;            // 786,432
    float* Wh1T = Wi1T + 786432;            // 786,432
    float* lastWT = Wh1T + 786432;          // 131,072
    float* embWT = lastWT + 131072;         // 131,072
    float* gi_emb = embWT + 131072;         // 786,432 (16 steps)
    float* gi_ctx = gi_emb + 786432;        // 49,152
    float* h0buf = gi_ctx + 49152;          // 32,768
    float* h1buf = h0buf + 32768;           // 32,768

    // --- weight transposes ---
    transpose_kernel<<<dim3(16, 16), 256, 0, stream>>>(Wq, WqT, 512, 512, 512);
    transpose_kernel<<<dim3(16, 16), 256, 0, stream>>>(Wk, WkT, 512, 512, 512);
    transpose_kernel<<<dim3(48, 16), 256, 0, stream>>>(Wi0, Wi0aT, 1536, 512, 1024);
    transpose_kernel<<<dim3(48, 16), 256, 0, stream>>>(Wi0 + 512, Wi0bT, 1536, 512, 1024);
    transpose_kernel<<<dim3(48, 16), 256, 0, stream>>>(Wh0, Wh0T, 1536, 512, 512);
    transpose_kernel<<<dim3(48, 16), 256, 0, stream>>>(Wi1, Wi1T, 1536, 512, 512);
    transpose_kernel<<<dim3(48, 16), 256, 0, stream>>>(Wh1, Wh1T, 1536, 512, 512);
    transpose_kernel<<<dim3(8, 16), 256, 0, stream>>>(last_W, lastWT, 256, 512, 512);
    transpose_kernel<<<dim3(16, 8), 256, 0, stream>>>(emb_W, embWT, 512, 256, 256);

    kproj_gemm_kernel<<<dim3(64, 8), 256, 0, stream>>>(enc, WkT, kpT);
    init_kernel<<<B, 512, 0, stream>>>(hidden, embWT, emb_b, Wi0bT, h0buf, h1buf, gi_emb);

    int p0 = 0, p1 = 0;
    for (int i = 0; i < STEPS; ++i) {
        int nb_attn = 32;
        int grid = (i == 0) ? 32 : 64;
        attn_tail_kernel<<<grid, 512, 0, stream>>>(
            nb_attn, h1buf + (size_t)p1 * BH, WqT, kpT, wv, enc, Wi0aT, bi0, gi_ctx,
            out_attn + (size_t)i * B * T, lastWT, last_b,
            target + (size_t)(i > 0 ? i - 1 : 0) * B * ODIM, tmask + (i > 0 ? i - 1 : 0) * B,
            embWT, emb_b, Wi0bT, out + (size_t)(i > 0 ? i - 1 : 0) * B * ODIM,
            gi_emb + (size_t)i * B * G3, 1);
        for (int t = 0; t <= i + 1; ++t) {
            int nb0 = (t <= i) ? 128 : 0;
            int nb1 = (t >= 1) ? 128 : 0;
            int tge = (t < 15) ? t : 15;
            cell_kernel<<<nb0 + nb1, 256, 0, stream>>>(
                nb0, h0buf + (size_t)p0 * BH, h0buf + (size_t)(p0 ^ 1) * BH,
                h1buf + (size_t)p1 * BH, h1buf + (size_t)(p1 ^ 1) * BH,
                gi_emb + (size_t)tge * B * G3, gi_ctx, Wh0T, bh0, Wi1T, bi1, Wh1T, bh1);
            if (nb0) p0 ^= 1;
            if (nb1) p1 ^= 1;
        }
    }
    // final tail (step 15), no next embedding needed
    attn_tail_kernel<<<32, 512, 0, stream>>>(
        0, h1buf + (size_t)p1 * BH, WqT, kpT, wv, enc, Wi0aT, bi0, gi_ctx, out_attn,
        lastWT, last_b, target + (size_t)15 * B * ODIM, tmask + 15 * B, embWT, emb_b, Wi0bT,
        out + (size_t)15 * B * ODIM, gi_emb, 0);
    copy_hidden_kernel<<<64, 256, 0, stream>>>(h0buf + (size_t)p0 * BH, h1buf + (size_t)p1 * BH,
                                               out_hidden);
}

// Round 3
// 3524.272 us; speedup vs baseline: 4.8054x; 1.5179x over previous
//
#include <hip/hip_runtime.h>
#include <math.h>

#define B 32
#define T 128
#define H 512
#define E 512
#define ODIM 256
#define STEPS 16
#define G3 1536  // 3*H
#define BH (B * H)

typedef float4 f4;

__device__ __forceinline__ float sigmoidf_(float x) { return 1.0f / (1.0f + __expf(-x)); }
__device__ __forceinline__ void fma4(f4& a, float s, const f4 w) {
    a.x = fmaf(s, w.x, a.x); a.y = fmaf(s, w.y, a.y);
    a.z = fmaf(s, w.z, a.z); a.w = fmaf(s, w.w, a.w);
}
__device__ __forceinline__ void add4(f4& a, const f4 b) {
    a.x += b.x; a.y += b.y; a.z += b.z; a.w += b.w;
}

// ---------------- generic 32x32 tiled transpose: out[c*R+r] = in[r*ldin+c] ----------------
__global__ void transpose_kernel(const float* __restrict__ in, float* __restrict__ out,
                                 int R, int C, int ldin) {
    __shared__ float tile[32][33];
    int r0 = blockIdx.x * 32, c0 = blockIdx.y * 32;
    int tx = threadIdx.x & 31, ty = threadIdx.x >> 5;  // 32x8
#pragma unroll
    for (int k = 0; k < 4; ++k) {
        int r = r0 + ty + k * 8;
        tile[ty + k * 8][tx] = in[(size_t)r * ldin + c0 + tx];
    }
    __syncthreads();
#pragma unroll
    for (int k = 0; k < 4; ++k) {
        int c = c0 + ty + k * 8;
        out[(size_t)c * R + r0 + tx] = tile[tx][ty + k * 8];
    }
}

// ---------------- kpT[b][c][t] = sum_k enc[b*T+t][k] * WkT[k][c] ----------------
__global__ void __launch_bounds__(256) kproj_gemm_kernel(const float* __restrict__ A,
                                                         const float* __restrict__ Bt,
                                                         float* __restrict__ kpT) {
    __shared__ float As[64][68];
    __shared__ float Bs[64][64];
    int r0 = blockIdx.x * 64, c0 = blockIdx.y * 64;
    int tid = threadIdx.x;
    int tx = tid & 15, ty = tid >> 4;  // 16x16, 4x4 micro-tile
    float acc[4][4] = {};
    for (int k0 = 0; k0 < 512; k0 += 64) {
#pragma unroll
        for (int i = 0; i < 4; ++i) {
            int row = i * 16 + ty, col = tx * 4;
            f4 av = *(const f4*)(A + (size_t)(r0 + row) * 512 + k0 + col);
            As[row][col] = av.x; As[row][col + 1] = av.y; As[row][col + 2] = av.z; As[row][col + 3] = av.w;
            f4 bv = *(const f4*)(Bt + (size_t)(k0 + row) * 512 + c0 + col);
            *(f4*)&Bs[row][col] = bv;
        }
        __syncthreads();
#pragma unroll 8
        for (int kk = 0; kk < 64; ++kk) {
            float a[4];
#pragma unroll
            for (int i = 0; i < 4; ++i) a[i] = As[ty * 4 + i][kk];
            f4 bv = *(const f4*)&Bs[kk][tx * 4];
#pragma unroll
            for (int i = 0; i < 4; ++i) {
                acc[i][0] += a[i] * bv.x; acc[i][1] += a[i] * bv.y;
                acc[i][2] += a[i] * bv.z; acc[i][3] += a[i] * bv.w;
            }
        }
        __syncthreads();
    }
#pragma unroll
    for (int i = 0; i < 4; ++i) {
        int r = r0 + ty * 4 + i;
        int b = r >> 7, t = r & 127;
#pragma unroll
        for (int j = 0; j < 4; ++j) {
            int c = c0 + tx * 4 + j;
            kpT[((size_t)b * H + c) * T + t] = acc[i][j];
        }
    }
}

// ---------------- init: copy hidden, inp0 = emb(ones), gi_emb0 ----------------
__global__ void __launch_bounds__(512) init_kernel(const float* __restrict__ hidden,
                                                   const float* __restrict__ embWT,
                                                   const float* __restrict__ emb_b,
                                                   const float* __restrict__ Wi0bT,
                                                   float* __restrict__ h0, float* __restrict__ h1,
                                                   float* __restrict__ gi_emb0) {
    __shared__ float sh_inp[E];
    int b = blockIdx.x, tid = threadIdx.x;
    h0[b * H + tid] = hidden[b * H + tid];
    h1[b * H + tid] = hidden[BH + b * H + tid];
    float acc = emb_b[tid];
#pragma unroll 8
    for (int o = 0; o < ODIM; ++o) acc += embWT[o * E + tid];
    sh_inp[tid] = acc;
    __syncthreads();
    float a0 = 0.f, a1 = 0.f, a2 = 0.f;
    int g = tid;
#pragma unroll 8
    for (int e = 0; e < E; ++e) {
        float c = sh_inp[e];
        const float* w = Wi0bT + e * G3 + g;
        a0 += c * w[0]; a1 += c * w[512]; a2 += c * w[1024];
    }
    gi_emb0[b * G3 + g] = a0;
    gi_emb0[b * G3 + 512 + g] = a1;
    gi_emb0[b * G3 + 1024 + g] = a2;
}

// ---------------- attn (blocks < nb_attn) + tail for prev step (blocks >= nb_attn) ----------------
__global__ void __launch_bounds__(512) attn_tail_kernel(
    int nb_attn, const float* __restrict__ h1_cur,
    const float* __restrict__ WqT, const float* __restrict__ kpT, const float* __restrict__ wv,
    const float* __restrict__ enc, const float* __restrict__ Wi0aT, const float* __restrict__ bi0,
    float* __restrict__ gi_ctx, float* __restrict__ attn_out,
    const float* __restrict__ lastWT, const float* __restrict__ last_b,
    const float* __restrict__ target_step, const int* __restrict__ mask_step,
    const float* __restrict__ embWT, const float* __restrict__ emb_b,
    const float* __restrict__ Wi0bT, float* __restrict__ out_step,
    float* __restrict__ gi_emb_next, int do_emb) {
    __shared__ __align__(16) float sh_h[H];
    __shared__ __align__(16) float sh_q[H];
    __shared__ __align__(16) float sh_wv[H];
    __shared__ __align__(16) float sh_ctx[H];
    __shared__ __align__(16) float sh_f[ODIM];
    __shared__ __align__(16) float sh_inp[E];
    __shared__ float sh_sc[T];
    __shared__ float sh_w[T];
    __shared__ float sh_red[2];
    __shared__ __align__(16) float part[6144];
    f4* part4 = (f4*)part;
    int tid = threadIdx.x;  // 512
    if ((int)blockIdx.x < nb_attn) {
        int b = blockIdx.x;
        sh_h[tid] = h1_cur[b * H + tid];
        sh_wv[tid] = wv[tid];
        __syncthreads();
        // ---- q-proj: thread (q = tid&127, ks = tid>>7), 128 k-iters f4 ----
        {
            int q = tid & 127, ks = tid >> 7;
            const f4* w4 = (const f4*)WqT;
            f4 acc = {0, 0, 0, 0};
            int k0 = ks * 128;
#pragma unroll 8
            for (int k = k0; k < k0 + 128; ++k) fma4(acc, sh_h[k], w4[(size_t)k * 128 + q]);
            part4[tid] = acc;
        }
        __syncthreads();
        if (tid < 128) {
            f4 s = part4[tid];
            add4(s, part4[128 + tid]); add4(s, part4[256 + tid]); add4(s, part4[384 + tid]);
            ((f4*)sh_q)[tid] = s;
        }
        __syncthreads();
        // ---- scores: thread (grp = tid>>7, t = tid&127) ----
        {
            int grp = tid >> 7, t = tid & 127;
            const float* kp = kpT + (size_t)b * H * T + t;
            float sa = 0.f;
#pragma unroll 4
            for (int jj = 0; jj < 128; ++jj) {
                int j = grp * 128 + jj;
                sa += tanhf(sh_q[j] + kp[(size_t)j * T]) * sh_wv[j];
            }
            part[tid] = sa;
        }
        __syncthreads();
        if (tid < T) sh_sc[tid] = part[tid] + part[tid + 128] + part[tid + 256] + part[tid + 384];
        __syncthreads();
        if (tid < 64) {
            float m = fmaxf(sh_sc[tid], sh_sc[tid + 64]);
            for (int off = 32; off; off >>= 1) m = fmaxf(m, __shfl_xor(m, off));
            if (tid == 0) sh_red[0] = m;
        }
        __syncthreads();
        if (tid < T) sh_w[tid] = __expf(sh_sc[tid] - sh_red[0]);
        __syncthreads();
        if (tid < 64) {
            float s = sh_w[tid] + sh_w[tid + 64];
            for (int off = 32; off; off >>= 1) s += __shfl_xor(s, off);
            if (tid == 0) sh_red[1] = s;
        }
        __syncthreads();
        if (tid < T) {
            float w = sh_w[tid] / sh_red[1];
            sh_w[tid] = w;
            attn_out[b * T + tid] = w;
        }
        __syncthreads();
        // ---- ctx: thread (q = tid&127 c-quad, ts = tid>>7), 32 t-iters f4 ----
        {
            int q = tid & 127, ts = tid >> 7;
            const f4* e4 = (const f4*)enc;
            f4 acc = {0, 0, 0, 0};
            int t0 = ts * 32;
#pragma unroll 8
            for (int t = t0; t < t0 + 32; ++t) fma4(acc, sh_w[t], e4[((size_t)b * T + t) * 128 + q]);
            part4[tid] = acc;
        }
        __syncthreads();
        if (tid < 128) {
            f4 s = part4[tid];
            add4(s, part4[128 + tid]); add4(s, part4[256 + tid]); add4(s, part4[384 + tid]);
            ((f4*)sh_ctx)[tid] = s;
        }
        __syncthreads();
        // ---- gi_ctx: 3 gates, thread (q = tid&127, ks = tid>>7), 128 k-iters x 3 f4 ----
        {
            int q = tid & 127, ks = tid >> 7;
            const f4* w4 = (const f4*)Wi0aT;
            f4 a0 = {0, 0, 0, 0}, a1 = {0, 0, 0, 0}, a2 = {0, 0, 0, 0};
            int k0 = ks * 128;
#pragma unroll 4
            for (int k = k0; k < k0 + 128; ++k) {
                float c = sh_ctx[k];
                const f4* wp = w4 + (size_t)k * 384 + q;
                fma4(a0, c, wp[0]); fma4(a1, c, wp[128]); fma4(a2, c, wp[256]);
            }
            part4[tid * 3] = a0; part4[tid * 3 + 1] = a1; part4[tid * 3 + 2] = a2;
        }
        __syncthreads();
        if (tid < 384) {
            int g = tid >> 7, q = tid & 127;
            f4 s = part4[q * 3 + g];
            add4(s, part4[(128 + q) * 3 + g]);
            add4(s, part4[(256 + q) * 3 + g]);
            add4(s, part4[(384 + q) * 3 + g]);
            add4(s, ((const f4*)bi0)[g * 128 + q]);
            ((f4*)(gi_ctx + (size_t)b * G3))[g * 128 + q] = s;
        }
    } else {
        int b = blockIdx.x - nb_attn;
        sh_h[tid] = h1_cur[b * H + tid];
        __syncthreads();
        // ---- lin: thread (q = tid&63 o-quad, ks = tid>>6), 64 k-iters f4 ----
        {
            int q = tid & 63, ks = tid >> 6;
            const f4* w4 = (const f4*)lastWT;
            f4 acc = {0, 0, 0, 0};
            int k0 = ks * 64;
#pragma unroll 8
            for (int k = k0; k < k0 + 64; ++k) fma4(acc, sh_h[k], w4[(size_t)k * 64 + q]);
            part4[tid] = acc;
        }
        __syncthreads();
        if (tid < 64) {
            f4 s = part4[tid];
#pragma unroll
            for (int ks = 1; ks < 8; ++ks) add4(s, part4[ks * 64 + tid]);
            add4(s, ((const f4*)last_b)[tid]);
            f4 tg = ((const f4*)(target_step + (size_t)b * ODIM))[tid];
            int msk = mask_step[b];
            f4 f;
            f.x = msk ? tg.x : s.x; f.y = msk ? tg.y : s.y;
            f.z = msk ? tg.z : s.z; f.w = msk ? tg.w : s.w;
            ((f4*)(out_step + (size_t)b * ODIM))[tid] = f;
            ((f4*)sh_f)[tid] = f;
        }
        __syncthreads();
        if (!do_emb) return;
        // ---- emb: thread (q = tid&127 e-quad, ks = tid>>7), 64 o-iters f4 ----
        {
            int q = tid & 127, ks = tid >> 7;
            const f4* w4 = (const f4*)embWT;
            f4 acc = {0, 0, 0, 0};
            int o0 = ks * 64;
#pragma unroll 8
            for (int o = o0; o < o0 + 64; ++o) fma4(acc, sh_f[o], w4[(size_t)o * 128 + q]);
            part4[tid] = acc;
        }
        __syncthreads();
        if (tid < 128) {
            f4 s = part4[tid];
            add4(s, part4[128 + tid]); add4(s, part4[256 + tid]); add4(s, part4[384 + tid]);
            add4(s, ((const f4*)emb_b)[tid]);
            ((f4*)sh_inp)[tid] = s;
        }
        __syncthreads();
        // ---- gi_emb_next: thread (q = tid&127, ks = tid>>7), 128 k-iters x 3 f4 ----
        {
            int q = tid & 127, ks = tid >> 7;
            const f4* w4 = (const f4*)Wi0bT;
            f4 a0 = {0, 0, 0, 0}, a1 = {0, 0, 0, 0}, a2 = {0, 0, 0, 0};
            int k0 = ks * 128;
#pragma unroll 4
            for (int k = k0; k < k0 + 128; ++k) {
                float c = sh_inp[k];
                const f4* wp = w4 + (size_t)k * 384 + q;
                fma4(a0, c, wp[0]); fma4(a1, c, wp[128]); fma4(a2, c, wp[256]);
            }
            part4[tid * 3] = a0; part4[tid * 3 + 1] = a1; part4[tid * 3 + 2] = a2;
        }
        __syncthreads();
        if (tid < 384) {
            int g = tid >> 7, q = tid & 127;
            f4 s = part4[q * 3 + g];
            add4(s, part4[(128 + q) * 3 + g]);
            add4(s, part4[(256 + q) * 3 + g]);
            add4(s, part4[(384 + q) * 3 + g]);
            ((f4*)(gi_emb_next + (size_t)b * G3))[g * 128 + q] = s;
        }
    }
}

// ---------------- fused dual GRU cell, f4 loads + deep k-split ----------------
// layer0 blocks [0,nb0): nb0 = 32b x 4 jchunks(128 j) ; thread (q=tid&31, ks=tid>>5 in [0,8))
// layer1 blocks [nb0, nb0+256): 32b x 8 jchunks(64 j) ; thread (q=tid&15, ks=tid>>4 in [0,16))
__global__ void __launch_bounds__(256) cell_kernel(
    int nb0,
    const float* __restrict__ h0_src, float* __restrict__ h0_dst,
    const float* __restrict__ h1_src, float* __restrict__ h1_dst,
    const float* __restrict__ gi_emb_t, const float* __restrict__ gi_ctx,
    const float* __restrict__ Wh0T, const float* __restrict__ bh0,
    const float* __restrict__ Wi1T, const float* __restrict__ bi1,
    const float* __restrict__ Wh1T, const float* __restrict__ bh1) {
    __shared__ __align__(16) float sh[7680];
    int tid = threadIdx.x;
    if ((int)blockIdx.x < nb0) {
        int bid = blockIdx.x;
        int b = bid >> 2, jc = bid & 3;
        if (tid < 128) ((f4*)sh)[tid] = ((const f4*)(h0_src + (size_t)b * H))[tid];
        __syncthreads();
        int q = tid & 31, ks = tid >> 5;
        const f4* w4 = (const f4*)Wh0T;
        int cbase = jc * 32 + q;
        f4 a0 = {0, 0, 0, 0}, a1 = {0, 0, 0, 0}, a2 = {0, 0, 0, 0};
        int k0 = ks * 64;
#pragma unroll 4
        for (int k = k0; k < k0 + 64; ++k) {
            float h = sh[k];
            const f4* wp = w4 + (size_t)k * 384 + cbase;
            fma4(a0, h, wp[0]); fma4(a1, h, wp[128]); fma4(a2, h, wp[256]);
        }
        f4* part = (f4*)(sh + 512);
        part[tid * 3] = a0; part[tid * 3 + 1] = a1; part[tid * 3 + 2] = a2;
        __syncthreads();
        float* red = sh + 3584;
        if (tid < 96) {
            int g = tid >> 5, qq = tid & 31;
            f4 s = part[qq * 3 + g];
#pragma unroll
            for (int k = 1; k < 8; ++k) add4(s, part[(k * 32 + qq) * 3 + g]);
            ((f4*)red)[g * 32 + qq] = s;
        }
        __syncthreads();
        if (tid < 128) {
            int j = jc * 128 + tid;
            float ghr = red[tid] + bh0[j];
            float ghz = red[128 + tid] + bh0[H + j];
            float ghn = red[256 + tid] + bh0[2 * H + j];
            float gir = gi_ctx[b * G3 + j] + gi_emb_t[b * G3 + j];
            float giz = gi_ctx[b * G3 + H + j] + gi_emb_t[b * G3 + H + j];
            float gin = gi_ctx[b * G3 + 2 * H + j] + gi_emb_t[b * G3 + 2 * H + j];
            float r = sigmoidf_(gir + ghr);
            float z = sigmoidf_(giz + ghz);
            float n = tanhf(gin + r * ghn);
            h0_dst[b * H + j] = (1.0f - z) * n + z * sh[j];
        }
    } else {
        int bid = blockIdx.x - nb0;
        int b = bid >> 3, jc = bid & 7;
        if (tid < 128) {
            ((f4*)sh)[tid] = ((const f4*)(h0_src + (size_t)b * H))[tid];          // x = y0
            ((f4*)(sh + 512))[tid] = ((const f4*)(h1_src + (size_t)b * H))[tid];  // h1
        }
        __syncthreads();
        int q = tid & 15, ks = tid >> 4;
        int cbase = jc * 16 + q;
        const f4* wi = (const f4*)Wi1T;
        const f4* wh = (const f4*)Wh1T;
        f4 i0 = {0, 0, 0, 0}, i1 = {0, 0, 0, 0}, i2 = {0, 0, 0, 0};
        f4 g0 = {0, 0, 0, 0}, g1 = {0, 0, 0, 0}, g2 = {0, 0, 0, 0};
        int k0 = ks * 32;
#pragma unroll 4
        for (int k = k0; k < k0 + 32; ++k) {
            float x = sh[k], hh = sh[512 + k];
            const f4* wip = wi + (size_t)k * 384 + cbase;
            const f4* whp = wh + (size_t)k * 384 + cbase;
            fma4(i0, x, wip[0]); fma4(i1, x, wip[128]); fma4(i2, x, wip[256]);
            fma4(g0, hh, whp[0]); fma4(g1, hh, whp[128]); fma4(g2, hh, whp[256]);
        }
        f4* part = (f4*)(sh + 1024);
        f4* p6 = part + tid * 6;
        p6[0] = i0; p6[1] = i1; p6[2] = i2; p6[3] = g0; p6[4] = g1; p6[5] = g2;
        __syncthreads();
        float* red = sh + 7168;
        if (tid < 96) {
            int m = tid >> 4, qq = tid & 15;
            f4 s = part[qq * 6 + m];
#pragma unroll
            for (int k = 1; k < 16; ++k) add4(s, part[(k * 16 + qq) * 6 + m]);
            ((f4*)red)[m * 16 + qq] = s;
        }
        __syncthreads();
        if (tid < 64) {
            int j = jc * 64 + tid;
            float ir = red[tid] + bi1[j];
            float iz = red[64 + tid] + bi1[H + j];
            float in_ = red[128 + tid] + bi1[2 * H + j];
            float hr = red[192 + tid] + bh1[j];
            float hz = red[256 + tid] + bh1[H + j];
            float hn = red[320 + tid] + bh1[2 * H + j];
            float r = sigmoidf_(ir + hr);
            float z = sigmoidf_(iz + hz);
            float n = tanhf(in_ + r * hn);
            h1_dst[b * H + j] = (1.0f - z) * n + z * sh[512 + j];
        }
    }
}

__global__ void copy_hidden_kernel(const float* __restrict__ h0, const float* __restrict__ h1,
                                   float* __restrict__ dst) {
    int i = blockIdx.x * 256 + threadIdx.x;
    dst[i] = h0[i];
    dst[BH + i] = h1[i];
}

extern "C" void kernel_launch(void* const* d_in, const int* in_sizes, int n_in,
                              void* d_out_v, int out_size, void* d_ws, size_t ws_size,
                              hipStream_t stream) {
    const float* enc = (const float*)d_in[0];
    const float* hidden = (const float*)d_in[1];
    const float* target = (const float*)d_in[2];
    const float* Wq = (const float*)d_in[3];
    const float* Wk = (const float*)d_in[4];
    const float* wv = (const float*)d_in[5];
    const float* emb_W = (const float*)d_in[6];
    const float* emb_b = (const float*)d_in[7];
    const float* Wi0 = (const float*)d_in[8];
    const float* Wh0 = (const float*)d_in[9];
    const float* bi0 = (const float*)d_in[10];
    const float* bh0 = (const float*)d_in[11];
    const float* Wi1 = (const float*)d_in[12];
    const float* Wh1 = (const float*)d_in[13];
    const float* bi1 = (const float*)d_in[14];
    const float* bh1 = (const float*)d_in[15];
    const float* last_W = (const float*)d_in[16];
    const float* last_b = (const float*)d_in[17];
    const int* tmask = (const int*)d_in[18];

    float* out = (float*)d_out_v;
    float* out_hidden = out + (size_t)STEPS * B * ODIM;
    float* out_attn = out_hidden + (size_t)2 * BH;

    float* ws = (float*)d_ws;
    float* kpT = ws;                        // 2,097,152
    float* WqT = kpT + 2097152;             // 262,144
    float* WkT = WqT + 262144;              // 262,144
    float* Wi0aT = WkT + 262144;            // 786,432
    float* Wi0bT = Wi0aT + 786432;          // 786,432
    float* Wh0T = Wi0bT + 786432;           // 786,432
    float* Wi1T = Wh0T + 786432;            // 786,432
    float* Wh1T = Wi1T + 786432;            // 786,432
    float* lastWT = Wh1T + 786432;          // 131,072
    float* embWT = lastWT + 131072;         // 131,072
    float* gi_emb = embWT + 131072;         // 786,432 (16 steps)
    float* gi_ctx = gi_emb + 786432;        // 49,152
    float* h0buf = gi_ctx + 49152;          // 32,768
    float* h1buf = h0buf + 32768;           // 32,768

    // --- weight transposes ---
    transpose_kernel<<<dim3(16, 16), 256, 0, stream>>>(Wq, WqT, 512, 512, 512);
    transpose_kernel<<<dim3(16, 16), 256, 0, stream>>>(Wk, WkT, 512, 512, 512);
    transpose_kernel<<<dim3(48, 16), 256, 0, stream>>>(Wi0, Wi0aT, 1536, 512, 1024);
    transpose_kernel<<<dim3(48, 16), 256, 0, stream>>>(Wi0 + 512, Wi0bT, 1536, 512, 1024);
    transpose_kernel<<<dim3(48, 16), 256, 0, stream>>>(Wh0, Wh0T, 1536, 512, 512);
    transpose_kernel<<<dim3(48, 16), 256, 0, stream>>>(Wi1, Wi1T, 1536, 512, 512);
    transpose_kernel<<<dim3(48, 16), 256, 0, stream>>>(Wh1, Wh1T, 1536, 512, 512);
    transpose_kernel<<<dim3(8, 16), 256, 0, stream>>>(last_W, lastWT, 256, 512, 512);
    transpose_kernel<<<dim3(16, 8), 256, 0, stream>>>(emb_W, embWT, 512, 256, 256);

    kproj_gemm_kernel<<<dim3(64, 8), 256, 0, stream>>>(enc, WkT, kpT);
    init_kernel<<<B, 512, 0, stream>>>(hidden, embWT, emb_b, Wi0bT, h0buf, h1buf, gi_emb);

    int p0 = 0, p1 = 0;
    for (int i = 0; i < STEPS; ++i) {
        int grid = (i == 0) ? 32 : 64;
        attn_tail_kernel<<<grid, 512, 0, stream>>>(
            32, h1buf + (size_t)p1 * BH, WqT, kpT, wv, enc, Wi0aT, bi0, gi_ctx,
            out_attn + (size_t)i * B * T, lastWT, last_b,
            target + (size_t)(i > 0 ? i - 1 : 0) * B * ODIM, tmask + (i > 0 ? i - 1 : 0) * B,
            embWT, emb_b, Wi0bT, out + (size_t)(i > 0 ? i - 1 : 0) * B * ODIM,
            gi_emb + (size_t)i * B * G3, 1);
        for (int t = 0; t <= i + 1; ++t) {
            int nb0 = (t <= i) ? 128 : 0;
            int nb1 = (t >= 1) ? 256 : 0;
            int tge = (t < 15) ? t : 15;
            cell_kernel<<<nb0 + nb1, 256, 0, stream>>>(
                nb0, h0buf + (size_t)p0 * BH, h0buf + (size_t)(p0 ^ 1) * BH,
                h1buf + (size_t)p1 * BH, h1buf + (size_t)(p1 ^ 1) * BH,
                gi_emb + (size_t)tge * B * G3, gi_ctx, Wh0T, bh0, Wi1T, bi1, Wh1T, bh1);
            if (nb0) p0 ^= 1;
            if (nb1) p1 ^= 1;
        }
    }
    // final tail (step 15), tail-only launch
    attn_tail_kernel<<<32, 512, 0, stream>>>(
        0, h1buf + (size_t)p1 * BH, WqT, kpT, wv, enc, Wi0aT, bi0, gi_ctx, out_attn,
        lastWT, last_b, target + (size_t)15 * B * ODIM, tmask + 15 * B, embWT, emb_b, Wi0bT,
        out + (size_t)15 * B * ODIM, gi_emb, 0);
    copy_hidden_kernel<<<64, 256, 0, stream>>>(h0buf + (size_t)p0 * BH, h1buf + (size_t)p1 * BH,
                                               out_hidden);
}